// Round 2
// baseline (132.431 us; speedup 1.0000x reference)
//
#include <hip/hip_runtime.h>

// Problem constants (from reference)
constexpr int F     = 20;        // fields
constexpr int A     = 4;         // len(ACTION)
constexpr int M     = 4;         // sub-codebooks
constexpr int D     = 64;        // EMBED_DIM (= M * 16)
constexpr int MAXK  = 512;
constexpr int FIELD = 50000;
constexpr int V     = FIELD * F; // 1,000,000
constexpr int B     = 8192;

// One group of 16 threads per (b,f). Thread t in [0,16):
//   m  = t >> 2  (which sub-codebook's 16-float slice)
//   pg = t & 3   (which float4 within that slice)
// Each thread cooperatively loads one of the 16 k-indices (a = t>>2, m = t&3),
// then shuffles to get k[a][m] as needed.
__global__ __launch_bounds__(256)
void wsqe_kernel(const int* __restrict__ x,
                 const float* __restrict__ arch_prob,
                 const float* __restrict__ codebooks,
                 const int* __restrict__ cb_index,
                 float* __restrict__ out) {
    const int gid = blockIdx.x * 256 + threadIdx.x;
    const int t   = gid & 15;        // sub-lane within (b,f) group
    const int bf  = gid >> 4;        // b*F + f   (< B*F exactly, grid sized to fit)
    const int f   = bf % F;

    const int xo = x[bf] + f * FIELD;

    // Cooperative index load: sub-lane t holds kv = cb_index[a = t>>2][xo][m = t&3].
    // 4 lanes per 'a' read 16 contiguous bytes.
    const int kv = cb_index[(((t >> 2) * V + xo) << 2) + (t & 3)];

    const int m = t >> 2;

    // arch_prob row for this field, aligned 16B
    const float4 w = *reinterpret_cast<const float4*>(arch_prob + f * A);

    // base pointer into this field's codebook block, at column t*4 (= m*16 + pg*4)
    const float* cbase = codebooks + f * (MAXK * D) + (t << 2);

    const int base_lane = threadIdx.x & 48;  // group base within the 64-lane wave

    float4 acc = make_float4(0.f, 0.f, 0.f, 0.f);

    {
        const int k0 = __shfl(kv, base_lane + 0  + m);
        const float4 v = *reinterpret_cast<const float4*>(cbase + k0 * D);
        acc.x = fmaf(w.x, v.x, acc.x); acc.y = fmaf(w.x, v.y, acc.y);
        acc.z = fmaf(w.x, v.z, acc.z); acc.w = fmaf(w.x, v.w, acc.w);
    }
    {
        const int k1 = __shfl(kv, base_lane + 4  + m);
        const float4 v = *reinterpret_cast<const float4*>(cbase + k1 * D);
        acc.x = fmaf(w.y, v.x, acc.x); acc.y = fmaf(w.y, v.y, acc.y);
        acc.z = fmaf(w.y, v.z, acc.z); acc.w = fmaf(w.y, v.w, acc.w);
    }
    {
        const int k2 = __shfl(kv, base_lane + 8  + m);
        const float4 v = *reinterpret_cast<const float4*>(cbase + k2 * D);
        acc.x = fmaf(w.z, v.x, acc.x); acc.y = fmaf(w.z, v.y, acc.y);
        acc.z = fmaf(w.z, v.z, acc.z); acc.w = fmaf(w.z, v.w, acc.w);
    }
    {
        const int k3 = __shfl(kv, base_lane + 12 + m);
        const float4 v = *reinterpret_cast<const float4*>(cbase + k3 * D);
        acc.x = fmaf(w.w, v.x, acc.x); acc.y = fmaf(w.w, v.y, acc.y);
        acc.z = fmaf(w.w, v.z, acc.z); acc.w = fmaf(w.w, v.w, acc.w);
    }

    // coalesced float4 store; consecutive bf regions are contiguous
    *reinterpret_cast<float4*>(out + (size_t)bf * D + (t << 2)) = acc;
}

extern "C" void kernel_launch(void* const* d_in, const int* in_sizes, int n_in,
                              void* d_out, int out_size, void* d_ws, size_t ws_size,
                              hipStream_t stream) {
    const int*   x         = (const int*)d_in[0];
    const float* arch_prob = (const float*)d_in[1];
    const float* codebooks = (const float*)d_in[2];
    const int*   cb_index  = (const int*)d_in[3];
    float*       out       = (float*)d_out;

    // total threads = B*F*16 = 2,621,440 ; 256/block -> 10,240 blocks (exact)
    const int total  = B * F * 16;
    const int blocks = total / 256;
    wsqe_kernel<<<blocks, 256, 0, stream>>>(x, arch_prob, codebooks, cb_index, out);
}

// Round 4
// 131.475 us; speedup vs baseline: 1.0073x; 1.0073x over previous
//
#include <hip/hip_runtime.h>

// Problem constants (from reference)
constexpr int F     = 20;        // fields
constexpr int A     = 4;         // len(ACTION)
constexpr int M     = 4;         // sub-codebooks
constexpr int D     = 64;        // EMBED_DIM (= M * 16)
constexpr int MAXK  = 512;
constexpr int FIELD = 50000;
constexpr int V     = FIELD * F; // 1,000,000
constexpr int B     = 8192;
constexpr int G     = 4;         // (b,f) groups per thread (MLP batching)

// clang-native vector type: __builtin_nontemporal_store requires it
typedef float f32x4 __attribute__((ext_vector_type(4)));

// 16 threads per (b,f) group; each thread processes G consecutive bf's.
// Thread t in [0,16): owns output float4 at column t*4 (m = t>>2, pg = t&3).
// Cooperative index load: sub-lane t loads cb_index[a = t>>2][xo][m = t&3],
// distributed via __shfl within the 16-lane cluster.
__global__ __launch_bounds__(256)
void wsqe_kernel(const int* __restrict__ x,
                 const float* __restrict__ arch_prob,
                 const float* __restrict__ codebooks,
                 const int* __restrict__ cb_index,
                 float* __restrict__ out) {
    const int gid     = blockIdx.x * 256 + threadIdx.x;
    const int t       = gid & 15;          // sub-lane within cluster
    const int cluster = gid >> 4;
    const int bf0     = cluster * G;       // first bf of this thread's batch

    const int a_ = t >> 2;                 // which ACTION this lane gathers
    const int m_ = t & 3;                  // which sub-codebook this lane gathers

    // ---- batched x load: G consecutive ints, 16B aligned (bf0 % 4 == 0) ----
    const int4 xv = *reinterpret_cast<const int4*>(x + bf0);
    int xs[G] = {xv.x, xv.y, xv.z, xv.w};

    // field id per g (bf0 % F, incrementing with wrap)
    int fs[G];
    {
        int f0 = bf0 % F;
        #pragma unroll
        for (int g = 0; g < G; ++g) {
            fs[g] = f0;
            f0 = (f0 + 1 == F) ? 0 : f0 + 1;
        }
    }

    // ---- issue all G scattered cb_index gathers (independent, in flight) ----
    int kv[G];
    #pragma unroll
    for (int g = 0; g < G; ++g) {
        const int xo = xs[g] + fs[g] * FIELD;
        kv[g] = cb_index[((a_ * V + xo) << 2) + m_];
    }

    const int base_lane = threadIdx.x & 48;  // cluster base within the wave

    // ---- distribute indices via shuffle, issue all G*4 codebook loads ----
    const int m = t >> 2;                    // this thread's output sub-codebook
    float4 v[G][A];
    #pragma unroll
    for (int g = 0; g < G; ++g) {
        const float* cbase = codebooks + fs[g] * (MAXK * D) + (t << 2);
        #pragma unroll
        for (int a = 0; a < A; ++a) {
            const int k = __shfl(kv[g], base_lane + a * 4 + m);
            v[g][a] = *reinterpret_cast<const float4*>(cbase + k * D);
        }
    }

    // ---- weighted sums + nontemporal stores ----
    #pragma unroll
    for (int g = 0; g < G; ++g) {
        const float4 w = *reinterpret_cast<const float4*>(arch_prob + fs[g] * A);
        f32x4 acc;
        acc.x = w.x * v[g][0].x; acc.y = w.x * v[g][0].y;
        acc.z = w.x * v[g][0].z; acc.w = w.x * v[g][0].w;
        acc.x = fmaf(w.y, v[g][1].x, acc.x); acc.y = fmaf(w.y, v[g][1].y, acc.y);
        acc.z = fmaf(w.y, v[g][1].z, acc.z); acc.w = fmaf(w.y, v[g][1].w, acc.w);
        acc.x = fmaf(w.z, v[g][2].x, acc.x); acc.y = fmaf(w.z, v[g][2].y, acc.y);
        acc.z = fmaf(w.z, v[g][2].z, acc.z); acc.w = fmaf(w.z, v[g][2].w, acc.w);
        acc.x = fmaf(w.w, v[g][3].x, acc.x); acc.y = fmaf(w.w, v[g][3].y, acc.y);
        acc.z = fmaf(w.w, v[g][3].z, acc.z); acc.w = fmaf(w.w, v[g][3].w, acc.w);

        f32x4* dst = reinterpret_cast<f32x4*>(out + (size_t)(bf0 + g) * D + (t << 2));
        __builtin_nontemporal_store(acc, dst);
    }
}

extern "C" void kernel_launch(void* const* d_in, const int* in_sizes, int n_in,
                              void* d_out, int out_size, void* d_ws, size_t ws_size,
                              hipStream_t stream) {
    const int*   x         = (const int*)d_in[0];
    const float* arch_prob = (const float*)d_in[1];
    const float* codebooks = (const float*)d_in[2];
    const int*   cb_index  = (const int*)d_in[3];
    float*       out       = (float*)d_out;

    // clusters = B*F/G = 40,960 ; threads = 655,360 ; blocks = 2,560 (exact)
    const int total  = (B * F / G) * 16;
    const int blocks = total / 256;
    wsqe_kernel<<<blocks, 256, 0, stream>>>(x, arch_prob, codebooks, cb_index, out);
}